// Round 12
// baseline (645.858 us; speedup 1.0000x reference)
//
#include <hip/hip_runtime.h>
#include <hip/hip_bf16.h>

#define NN 50000
#define NE 500000
#define DH 128
#define INV_N (1.0f / 50000.0f)
#define NBUCK 98      // ceil(50000 / 512)
#define BSH 9         // bucket = dst >> 9
#define T1 4096       // edges per multisplit tile
#define NT1 ((NE + T1 - 1) / T1)  // 123
#define GGC 782       // (NN + 63) / 64 gemm blocks

using short8 = __attribute__((ext_vector_type(8))) short;
using f32x4 = __attribute__((ext_vector_type(4))) float;
typedef unsigned short u16;

__device__ __forceinline__ float b2f(unsigned short u) {
    unsigned v = (unsigned)u << 16;
    return __builtin_bit_cast(float, v);
}
__device__ __forceinline__ unsigned short f2b(float f) {
    return __builtin_bit_cast(unsigned short, __float2bfloat16(f));
}

struct EdgePtrs {
    const int* src[4];
    const int* dst[4];
    const float* val[4];
};

// ---------------- CSR build: bucketed counting sort (line-friendly writes) ------

__global__ void k_bhist(EdgePtrs ep, int* __restrict__ btot) {
    int r = blockIdx.y;
    const int* dst = ep.dst[r];
    __shared__ int h[NBUCK];
    int t = threadIdx.x;
    if (t < NBUCK) h[t] = 0;
    __syncthreads();
    int e0 = blockIdx.x * T1;
#pragma unroll
    for (int i = 0; i < T1 / 256; ++i) {
        int e = e0 + i * 256 + t;
        if (e < NE) atomicAdd(&h[dst[e] >> BSH], 1);
    }
    __syncthreads();
    if (t < NBUCK && h[t] > 0) atomicAdd(&btot[r * NBUCK + t], h[t]);
}

__global__ void k_bscan(const int* __restrict__ btot, int* __restrict__ bbase,
                        int* __restrict__ bcur) {
    __shared__ int s[128];
    int t = threadIdx.x;
    for (int r = 0; r < 4; ++r) {
        int v = (t < NBUCK) ? btot[r * NBUCK + t] : 0;
        if (t < 128) s[t] = v;
        __syncthreads();
        for (int off = 1; off < 128; off <<= 1) {
            int u = (t >= off && t < 128) ? s[t - off] : 0;
            __syncthreads();
            if (t < 128) s[t] += u;
            __syncthreads();
        }
        if (t < NBUCK) {
            int ex = s[t] - v;
            bbase[r * NBUCK + t] = ex;
            bcur[r * NBUCK + t] = ex;
        }
        __syncthreads();
    }
}

__global__ __launch_bounds__(256) void k_msplit(EdgePtrs ep, int* __restrict__ bcur,
                                                int2* __restrict__ esb) {
    int r = blockIdx.y;
    const int* src = ep.src[r];
    const int* dst = ep.dst[r];
    const float* val = ep.val[r];
    __shared__ int2 eb[T1];
    __shared__ int hist[128], lofs[128], lcur[128], sc[128], gbase[NBUCK];
    int t = threadIdx.x;
    int e0 = blockIdx.x * T1;
    int total = NE - e0;
    if (total > T1) total = T1;

    int sreg[T1 / 256], dreg[T1 / 256];
    float vreg[T1 / 256];
#pragma unroll
    for (int i = 0; i < T1 / 256; ++i) {
        int e = e0 + i * 256 + t;
        bool ok = e < NE;
        sreg[i] = ok ? src[e] : 0;
        dreg[i] = ok ? dst[e] : -1;
        vreg[i] = ok ? val[e] : 0.f;
    }
    if (t < 128) { hist[t] = 0; lcur[t] = 0; }
    __syncthreads();
#pragma unroll
    for (int i = 0; i < T1 / 256; ++i)
        if (dreg[i] >= 0) atomicAdd(&hist[dreg[i] >> BSH], 1);
    __syncthreads();
    if (t < 128) sc[t] = hist[t];
    __syncthreads();
    for (int off = 1; off < 128; off <<= 1) {
        int u = (t >= off && t < 128) ? sc[t - off] : 0;
        __syncthreads();
        if (t < 128) sc[t] += u;
        __syncthreads();
    }
    if (t < 128) lofs[t] = sc[t] - hist[t];
    __syncthreads();
#pragma unroll
    for (int i = 0; i < T1 / 256; ++i) {
        if (dreg[i] >= 0) {
            int b = dreg[i] >> BSH;
            int pos = lofs[b] + atomicAdd(&lcur[b], 1);
            eb[pos] = make_int2((int)(((unsigned)dreg[i] << 16) | (unsigned)sreg[i]),
                                __float_as_int(vreg[i]));
        }
    }
    __syncthreads();
    if (t < NBUCK && hist[t] > 0) gbase[t] = atomicAdd(&bcur[r * NBUCK + t], hist[t]);
    __syncthreads();
    for (int j = t; j < total; j += 256) {
        int2 rec = eb[j];
        int b = (int)((unsigned)rec.x >> (16 + BSH));
        esb[(size_t)r * NE + gbase[b] + (j - lofs[b])] = rec;
    }
}

__global__ __launch_bounds__(256) void k_blocal(const int2* __restrict__ esb,
                                                const int* __restrict__ btot,
                                                const int* __restrict__ bbase,
                                                int* __restrict__ rs4,
                                                int2* __restrict__ es4) {
    int r = blockIdx.y, b = blockIdx.x;
    int base = bbase[r * NBUCK + b];
    int cnt = btot[r * NBUCK + b];
    int d0 = b << BSH;
    int dlim = NN - d0;
    if (dlim > (1 << BSH)) dlim = 1 << BSH;
    __shared__ int h[512], pr[512], cur[512], ps[256];
    int t = threadIdx.x;
    h[t] = 0; h[t + 256] = 0;
    cur[t] = 0; cur[t + 256] = 0;
    __syncthreads();
    const int2* ein = esb + (size_t)r * NE + base;
    for (int j = t; j < cnt; j += 256)
        atomicAdd(&h[(int)((unsigned)ein[j].x >> 16) - d0], 1);
    __syncthreads();
    int a0 = h[2 * t], a1 = h[2 * t + 1];
    ps[t] = a0 + a1;
    __syncthreads();
    for (int off = 1; off < 256; off <<= 1) {
        int u = (t >= off) ? ps[t - off] : 0;
        __syncthreads();
        ps[t] += u;
        __syncthreads();
    }
    int ex = ps[t] - (a0 + a1);
    pr[2 * t] = ex;
    pr[2 * t + 1] = ex + a0;
    __syncthreads();
    for (int dl = t; dl < dlim; dl += 256) rs4[r * (NN + 1) + d0 + dl] = base + pr[dl];
    if (b == NBUCK - 1 && t == 0) rs4[r * (NN + 1) + NN] = NE;
    for (int j = t; j < cnt; j += 256) {
        int2 rec = ein[j];
        int dl = (int)((unsigned)rec.x >> 16) - d0;
        int k = atomicAdd(&cur[dl], 1);
        es4[(size_t)r * NE + base + pr[dl] + k] = make_int2(rec.x & 0xFFFF, rec.y);
    }
}

// ------------------------- fp32 -> bf16 bulk convert -------------------------

__global__ void k_f2b(const float* __restrict__ src, u16* __restrict__ dst, int n4) {
    int i = blockIdx.x * 256 + threadIdx.x;
    if (i >= n4) return;
    float4 v = ((const float4*)src)[i];
    unsigned lo = (unsigned)f2b(v.x) | ((unsigned)f2b(v.y) << 16);
    unsigned hi = (unsigned)f2b(v.z) | ((unsigned)f2b(v.w) << 16);
    ((uint2*)dst)[i] = make_uint2(lo, hi);
}

// ------------------------- weight transpose + swizzle pack -------------------------
// dst: bf16 at byte ((n*K + k)*2) ^ ((n&7)<<4)  -- matches GEMM's swizzled ds_read

struct WDesc { const float* src; u16* dst; int K; int N; int start; };
struct WPack { WDesc d[9]; };

__global__ void k_wt(WPack p) {
    int gid = blockIdx.x * 256 + threadIdx.x;
#pragma unroll
    for (int i = 0; i < 9; ++i) {
        int K = p.d[i].K, N = p.d[i].N;
        int local = gid - p.d[i].start;
        if (local >= 0 && local < K * N) {
            int k = local / N;
            int n = local - k * N;
            float w = p.d[i].src[local];
            unsigned byte = ((unsigned)(n * K + k) * 2u) ^ ((unsigned)(n & 7) << 4);
            *(u16*)((char*)p.d[i].dst + byte) = f2b(w);
            return;
        }
    }
}

// ------------------------- MFMA GEMM (optionally paired via gridDim.y) ----------
// MODE 0: Out = X@W + Bias ; MODE 1: relu ;
// MODE 2: Sout[blockIdx.x] = block partial of sum_rows(tanh(X@W+Bias)@Q)  (NO atomics)
template <int KT, int NF, int MODE, bool OUTF32>
__global__ __launch_bounds__(256) void k_mm(const u16* __restrict__ X0, const u16* __restrict__ X1,
                                            int M, const u16* __restrict__ WT,
                                            const float* __restrict__ Bias,
                                            const float* __restrict__ Q,
                                            void* __restrict__ O0, void* __restrict__ O1,
                                            float* __restrict__ S0, float* __restrict__ S1) {
    constexpr int K = KT * 32;
    constexpr int N = NF * 16;
    const u16* X = blockIdx.y ? X1 : X0;
    void* OutV = blockIdx.y ? O1 : O0;
    float* Sout = blockIdx.y ? S1 : S0;

    __shared__ u16 wlds[K * N];
    int t = threadIdx.x;
    constexpr int CH = K * N * 2 / 16;
    const uint4* wg = (const uint4*)WT;
    uint4* wl = (uint4*)wlds;
#pragma unroll
    for (int i = 0; i < CH / 256; ++i) wl[t + i * 256] = wg[t + i * 256];

    int l = t & 63, w = t >> 6;
    int m0 = blockIdx.x * 64 + w * 16;
    int arow = m0 + (l & 15);
    if (arow >= M) arow = M - 1;  // clamp; OOB rows masked in epilogue
    int kh = (l >> 4) * 8;

    short8 a[KT];
    const u16* xp = X + (size_t)arow * K + kh;
#pragma unroll
    for (int kt = 0; kt < KT; ++kt) a[kt] = *(const short8*)(xp + kt * 32);

    __syncthreads();

    f32x4 acc[NF];
#pragma unroll
    for (int i = 0; i < NF; ++i) acc[i] = (f32x4){0.f, 0.f, 0.f, 0.f};

    unsigned sw = (unsigned)((l & 7) << 4);
#pragma unroll
    for (int nf = 0; nf < NF; ++nf) {
        unsigned base = (unsigned)((nf * 16 + (l & 15)) * K) * 2u;
#pragma unroll
        for (int kt = 0; kt < KT; ++kt) {
            unsigned byte = (base + (unsigned)(kt * 32 + kh) * 2u) ^ sw;
            short8 b = *(const short8*)((const char*)wlds + byte);
            acc[nf] = __builtin_amdgcn_mfma_f32_16x16x32_bf16(a[kt], b, acc[nf], 0, 0, 0);
        }
    }

    // C/D layout: col=lane&15, row=(lane>>4)*4+r  [m89-verified]
    int col0 = l & 15;
    int rbase = m0 + (l >> 4) * 4;
    if (MODE == 2) {
        float tot = 0.f;
#pragma unroll
        for (int nf = 0; nf < NF; ++nf) {
            int c = nf * 16 + col0;
            float bv = Bias[c], qv = Q[c];
#pragma unroll
            for (int r = 0; r < 4; ++r)
                if (rbase + r < M) tot += tanhf(acc[nf][r] + bv) * qv;
        }
#pragma unroll
        for (int m = 1; m < 64; m <<= 1) tot += __shfl_xor(tot, m);
        __shared__ float wred[4];
        if (l == 0) wred[w] = tot;
        __syncthreads();
        if (t == 0) Sout[blockIdx.x] = wred[0] + wred[1] + wred[2] + wred[3];
    } else {
#pragma unroll
        for (int nf = 0; nf < NF; ++nf) {
            int c = nf * 16 + col0;
            float bv = Bias[c];
#pragma unroll
            for (int r = 0; r < 4; ++r) {
                int row = rbase + r;
                if (row >= M) continue;
                float v = acc[nf][r] + bv;
                if (MODE == 1) v = fmaxf(v, 0.f);
                if (OUTF32)
                    ((float*)OutV)[(size_t)row * N + c] = v;
                else
                    ((u16*)OutV)[(size_t)row * N + c] = f2b(v);
            }
        }
    }
}

// ---------- SpMM dual-relation, quarter-wave edges (dwordx4 per lane) ----------
// Wave handles one dst row. Lane l: quarter q=l>>4 owns edge e+q of each group
// of 4; j=l&15 covers features [j*8, j*8+8) (16B). Cross-quarter shfl reduce.
struct SpmmDArgs {
    const int* rsA; const int2* esA; const u16* XsA;
    const int* rsB; const int2* esB; const u16* XsB;
    const u16* Xd; const float* a2A; const float* a2B;
    u16* out1; u16* out2;
};

__device__ __forceinline__ void acc8(float* a, uint4 x, float v) {
    unsigned d0 = x.x, d1 = x.y, d2 = x.z, d3 = x.w;
    a[0] += v * b2f((u16)d0); a[1] += v * b2f((u16)(d0 >> 16));
    a[2] += v * b2f((u16)d1); a[3] += v * b2f((u16)(d1 >> 16));
    a[4] += v * b2f((u16)d2); a[5] += v * b2f((u16)(d2 >> 16));
    a[6] += v * b2f((u16)d3); a[7] += v * b2f((u16)(d3 >> 16));
}

__global__ __launch_bounds__(256) void k_spmmD(SpmmDArgs p) {
    int row = blockIdx.x * 4 + (threadIdx.x >> 6);
    if (row >= NN) return;
    int l = threadIdx.x & 63;
    int q = l >> 4, j = l & 15;

    uint4 xd4 = *(const uint4*)&p.Xd[(size_t)row * DH + j * 8];
    float accA[8], accB[8];
#pragma unroll
    for (int c = 0; c < 8; ++c) { accA[c] = 0.f; accB[c] = 0.f; }
    if (q == 0) {
        float aA = p.a2A[row];
        acc8(accA, xd4, aA);
    } else if (q == 1) {
        float aB = p.a2B[row];
        acc8(accB, xd4, aB);
    }

    int eA = p.rsA[row], eAe = p.rsA[row + 1];
    int eB = p.rsB[row], eBe = p.rsB[row + 1];
    const int2 z2 = make_int2(0, 0);
    int2 rA = (eA + q < eAe) ? p.esA[eA + q] : z2;
    int2 rB = (eB + q < eBe) ? p.esB[eB + q] : z2;

    while (eA < eAe || eB < eBe) {
        bool doA = eA < eAe, doB = eB < eBe;
        int2 cA = rA, cB = rB;
        int nA = eA + 4, nB = eB + 4;
        // prefetch next group's records (independent of data loads below)
        rA = (doA && nA + q < eAe) ? p.esA[nA + q] : z2;
        rB = (doB && nB + q < eBe) ? p.esB[nB + q] : z2;
        if (doA) {
            uint4 x4 = *(const uint4*)&p.XsA[(size_t)cA.x * DH + j * 8];
            acc8(accA, x4, __int_as_float(cA.y));
            eA = nA;
        }
        if (doB) {
            uint4 x4 = *(const uint4*)&p.XsB[(size_t)cB.x * DH + j * 8];
            acc8(accB, x4, __int_as_float(cB.y));
            eB = nB;
        }
    }

    // cross-quarter reduce: lanes {j, j+16, j+32, j+48} hold same features
#pragma unroll
    for (int c = 0; c < 8; ++c) {
        accA[c] += __shfl_xor(accA[c], 16);
        accA[c] += __shfl_xor(accA[c], 32);
        accB[c] += __shfl_xor(accB[c], 16);
        accB[c] += __shfl_xor(accB[c], 32);
    }

    if (q == 0) {
        uint4 o1, o2;
        o1.x = (unsigned)f2b(accA[0]) | ((unsigned)f2b(accA[1]) << 16);
        o1.y = (unsigned)f2b(accA[2]) | ((unsigned)f2b(accA[3]) << 16);
        o1.z = (unsigned)f2b(accA[4]) | ((unsigned)f2b(accA[5]) << 16);
        o1.w = (unsigned)f2b(accA[6]) | ((unsigned)f2b(accA[7]) << 16);
        o2.x = (unsigned)f2b(accB[0]) | ((unsigned)f2b(accB[1]) << 16);
        o2.y = (unsigned)f2b(accB[2]) | ((unsigned)f2b(accB[3]) << 16);
        o2.z = (unsigned)f2b(accB[4]) | ((unsigned)f2b(accB[5]) << 16);
        o2.w = (unsigned)f2b(accB[6]) | ((unsigned)f2b(accB[7]) << 16);
        *(uint4*)&p.out1[(size_t)row * DH + j * 8] = o1;
        *(uint4*)&p.out2[(size_t)row * DH + j * 8] = o2;
    }
}

// --------- combine: reduce score partials in-block, beta softmax, stream --------

__global__ void k_combine(const u16* __restrict__ h1, const u16* __restrict__ h2,
                          const float* __restrict__ sp, u16* __restrict__ out, int n8) {
    int t = threadIdx.x;
    float p0 = 0.f, p1 = 0.f;
    for (int j = t; j < GGC; j += 256) {
        p0 += sp[j];
        p1 += sp[GGC + j];
    }
#pragma unroll
    for (int m = 1; m < 64; m <<= 1) {
        p0 += __shfl_xor(p0, m);
        p1 += __shfl_xor(p1, m);
    }
    __shared__ float r0[4], r1[4];
    if ((t & 63) == 0) {
        r0[t >> 6] = p0;
        r1[t >> 6] = p1;
    }
    __syncthreads();
    float s0 = (r0[0] + r0[1] + r0[2] + r0[3]) * INV_N;
    float s1 = (r1[0] + r1[1] + r1[2] + r1[3]) * INV_N;
    float mx = fmaxf(s0, s1);
    float ea = __expf(s0 - mx), eb = __expf(s1 - mx);
    float inv = 1.0f / (ea + eb);
    float b0 = ea * inv, b1 = eb * inv;

    int i = blockIdx.x * 256 + t;
    if (i >= n8) return;
    short8 A = ((const short8*)h1)[i];
    short8 B = ((const short8*)h2)[i];
    short8 O;
#pragma unroll
    for (int j = 0; j < 8; ++j) {
        float v = b0 * b2f((u16)A[j]) + b1 * b2f((u16)B[j]);
        O[j] = (short)f2b(fmaxf(v, 0.f));
    }
    ((short8*)out)[i] = O;
}

// ------------------------- launch -------------------------

extern "C" void kernel_launch(void* const* d_in, const int* in_sizes, int n_in, void* d_out,
                              int out_size, void* d_ws, size_t ws_size, hipStream_t stream) {
    (void)in_sizes; (void)n_in; (void)out_size; (void)ws_size;

    const float* x_A = (const float*)d_in[0];
    const float* x_B = (const float*)d_in[1];
    EdgePtrs ep;
    const float* a2I[4];
    for (int r = 0; r < 4; ++r) {  // AA, AB, BB, BA
        ep.src[r] = (const int*)d_in[2 + r * 4];
        ep.dst[r] = (const int*)d_in[3 + r * 4];
        ep.val[r] = (const float*)d_in[4 + r * 4];
        a2I[r] = (const float*)d_in[5 + r * 4];
    }
    const float* fc1A_w = (const float*)d_in[18];
    const float* fc1A_b = (const float*)d_in[19];
    const float* fc1B_w = (const float*)d_in[20];
    const float* fc1B_b = (const float*)d_in[21];
    const float* fcs_w[2] = {(const float*)d_in[22], (const float*)d_in[30]};
    const float* fcs_b[2] = {(const float*)d_in[23], (const float*)d_in[31]};
    const float* saA_w[2] = {(const float*)d_in[24], (const float*)d_in[32]};
    const float* saA_b[2] = {(const float*)d_in[25], (const float*)d_in[33]};
    const float* saA_q[2] = {(const float*)d_in[26], (const float*)d_in[34]};
    const float* saB_w[2] = {(const float*)d_in[27], (const float*)d_in[35]};
    const float* saB_b[2] = {(const float*)d_in[28], (const float*)d_in[36]};
    const float* saB_q[2] = {(const float*)d_in[29], (const float*)d_in[37]};
    const float* fc2_w = (const float*)d_in[38];
    const float* fc2_b = (const float*)d_in[39];

    char* p = (char*)d_ws;
    auto take = [&](size_t bytes) -> void* {
        void* r = (void*)p;
        p += (bytes + 255) & ~(size_t)255;
        return r;
    };
    const size_t NF = (size_t)NN * DH;
    u16* xAbf = (u16*)take((size_t)NN * 256 * 2);
    u16* xBbf = (u16*)take((size_t)NN * 128 * 2);
    u16* xA0 = (u16*)take(NF * 2);
    u16* xA1 = (u16*)take(NF * 2);
    u16* xB0 = (u16*)take(NF * 2);
    u16* xB1 = (u16*)take(NF * 2);
    u16* h1 = (u16*)take(NF * 2);
    u16* h2 = (u16*)take(NF * 2);
    u16* wt_fc1A = (u16*)take(256 * 128 * 2);
    u16* wt_fc1B = (u16*)take(128 * 128 * 2);
    u16* wt_fcs[2] = {(u16*)take(128 * 128 * 2), (u16*)take(128 * 128 * 2)};
    u16* wt_saA[2] = {(u16*)take(128 * 128 * 2), (u16*)take(128 * 128 * 2)};
    u16* wt_saB[2] = {(u16*)take(128 * 128 * 2), (u16*)take(128 * 128 * 2)};
    u16* wt_fc2 = (u16*)take(128 * 64 * 2);
    int* rs4 = (int*)take((size_t)(NN + 1) * 4 * 4);
    int2* es4 = (int2*)take((size_t)NE * 4 * 8);
    int2* esb = (int2*)take((size_t)NE * 4 * 8);
    int* btot = (int*)take(NBUCK * 4 * 4);
    int* bbase = (int*)take(NBUCK * 4 * 4);
    int* bcur = (int*)take(NBUCK * 4 * 4);
    float* spart[4];  // per-(hop,type) score partials: [2][GGC]
    for (int i = 0; i < 4; ++i) spart[i] = (float*)take(2 * GGC * 4);

    const int GG = GGC;                   // 782
    const int GP = (NN + 3) / 4;          // 12500
    const int GC8 = (int)(NF / 8 / 256);  // 3125

    const int* rsR[4];
    const int2* esR[4];
    for (int r = 0; r < 4; ++r) {
        rsR[r] = rs4 + r * (NN + 1);
        esR[r] = es4 + (size_t)r * NE;
    }

    // ---- CSR build: bucketed counting sort ----
    hipMemsetAsync(btot, 0, NBUCK * 4 * 4, stream);
    k_bhist<<<dim3(NT1, 4), 256, 0, stream>>>(ep, btot);
    k_bscan<<<1, 256, 0, stream>>>(btot, bbase, bcur);
    k_msplit<<<dim3(NT1, 4), 256, 0, stream>>>(ep, bcur, esb);
    k_blocal<<<dim3(NBUCK, 4), 256, 0, stream>>>(esb, btot, bbase, rs4, es4);

    // ---- input conversion + weight packing ----
    k_f2b<<<(NN * 256 / 4 + 255) / 256, 256, 0, stream>>>(x_A, xAbf, NN * 256 / 4);
    k_f2b<<<(NN * 128 / 4 + 255) / 256, 256, 0, stream>>>(x_B, xBbf, NN * 128 / 4);
    {
        WPack wp;
        const float* srcs_[9] = {fc1A_w, fc1B_w, fcs_w[0], fcs_w[1], saA_w[0],
                                 saA_w[1], saB_w[0], saB_w[1], fc2_w};
        u16* dsts_[9] = {wt_fc1A, wt_fc1B, wt_fcs[0], wt_fcs[1], wt_saA[0],
                         wt_saA[1], wt_saB[0], wt_saB[1], wt_fc2};
        int Ks[9] = {256, 128, 128, 128, 128, 128, 128, 128, 128};
        int Ns[9] = {128, 128, 128, 128, 128, 128, 128, 128, 64};
        int start = 0;
        for (int i = 0; i < 9; ++i) {
            wp.d[i] = {srcs_[i], dsts_[i], Ks[i], Ns[i], start};
            start += Ks[i] * Ns[i];
        }
        k_wt<<<(start + 255) / 256, 256, 0, stream>>>(wp);
    }

    // ---- fc1 + relu ----
    k_mm<8, 8, 1, false><<<dim3(GG, 1), 256, 0, stream>>>(xAbf, xAbf, NN, wt_fc1A, fc1A_b,
                                                          nullptr, xA0, xA0, nullptr, nullptr);
    k_mm<4, 8, 1, false><<<dim3(GG, 1), 256, 0, stream>>>(xBbf, xBbf, NN, wt_fc1B, fc1B_b,
                                                          nullptr, xB0, xB0, nullptr, nullptr);

    for (int h = 0; h < 2; ++h) {
        // shared per-hop linear: xA1 = xA0@fcs+b, xB1 = xB0@fcs+b (one dispatch)
        k_mm<4, 8, 0, false><<<dim3(GG, 2), 256, 0, stream>>>(xA0, xB0, NN, wt_fcs[h], fcs_b[h],
                                                              nullptr, xA1, xB1, nullptr, nullptr);
        // type A: AA (r=0) -> h1, AB (r=1) -> h2, both per wave
        {
            SpmmDArgs sa = {rsR[0], esR[0], xA1, rsR[1], esR[1], xB1,
                            xA1, a2I[0], a2I[1], h1, h2};
            k_spmmD<<<GP, 256, 0, stream>>>(sa);
        }
        k_mm<4, 8, 2, false><<<dim3(GG, 2), 256, 0, stream>>>(h1, h2, NN, wt_saA[h], saA_b[h],
                                                              saA_q[h], nullptr, nullptr,
                                                              spart[h * 2 + 0],
                                                              spart[h * 2 + 0] + GGC);
        k_combine<<<GC8, 256, 0, stream>>>(h1, h2, spart[h * 2 + 0], xA0, (int)(NF / 8));
        // type B: BB (r=2) -> h1, BA (r=3, gathers UPDATED xA0) -> h2
        {
            SpmmDArgs sb = {rsR[2], esR[2], xB1, rsR[3], esR[3], xA0,
                            xB1, a2I[2], a2I[3], h1, h2};
            k_spmmD<<<GP, 256, 0, stream>>>(sb);
        }
        k_mm<4, 8, 2, false><<<dim3(GG, 2), 256, 0, stream>>>(h1, h2, NN, wt_saB[h], saB_b[h],
                                                              saB_q[h], nullptr, nullptr,
                                                              spart[h * 2 + 1],
                                                              spart[h * 2 + 1] + GGC);
        k_combine<<<GC8, 256, 0, stream>>>(h1, h2, spart[h * 2 + 1], xB0, (int)(NF / 8));
    }

    // ---- fc2 (no relu), f32 out ----
    k_mm<4, 4, 0, true><<<dim3(GG, 1), 256, 0, stream>>>(xA0, xA0, NN, wt_fc2, fc2_b, nullptr,
                                                         d_out, d_out, nullptr, nullptr);
}